// Round 7
// baseline (308.206 us; speedup 1.0000x reference)
//
#include <hip/hip_runtime.h>
#include <math.h>

// ---------------------------------------------------------------------------
// ByteMultiHeadSelfAttention: B=2 S=2048 E=2048, H=16 KV=4 D=128, RoPE, causal.
// 4 launches:
//   prep:      convx (x fp32 -> xb bf16) + wconv (W -> W^T bf16), fused
//   gemm_qkv:  qkv = xb @ Wqkv, 128x128 tile, BK=32, 4-deep DMA pipeline with
//              counted vmcnt (T4) + FUSED epilogue: RoPE -> Qm/Km, V^T -> Vtm
//   flash2:    512 threads; 2 wave-groups split-KV (fixed-max softmax => adds),
//              32x32 MFMA, swapped QK^T, in-register P, paired q-tiles
//   gemm_bt:   out = attn @ Wo (fp32), same 4-deep pipeline
// ---------------------------------------------------------------------------

typedef __attribute__((ext_vector_type(8))) short short8;
typedef __attribute__((ext_vector_type(4))) float f32x4;
typedef __attribute__((ext_vector_type(16))) float f32x16;

typedef const __attribute__((address_space(1))) void* gvp;
typedef __attribute__((address_space(3))) void* svp;

__device__ __forceinline__ void async16(const void* g, void* l) {
  __builtin_amdgcn_global_load_lds((gvp)g, (svp)l, 16, 0, 0);
}
__device__ __forceinline__ void wait_vm0() { asm volatile("s_waitcnt vmcnt(0)" ::: "memory"); }
__device__ __forceinline__ void wait_vm4() { asm volatile("s_waitcnt vmcnt(4)" ::: "memory"); }
__device__ __forceinline__ void wait_vm8() { asm volatile("s_waitcnt vmcnt(8)" ::: "memory"); }
__device__ __forceinline__ void barrier_raw() { asm volatile("s_barrier" ::: "memory"); }

__device__ __forceinline__ unsigned short f2b(float f) {
  unsigned int u = __builtin_bit_cast(unsigned int, f);
  u += 0x7fffu + ((u >> 16) & 1u);   // RNE
  return (unsigned short)(u >> 16);
}
__device__ __forceinline__ float b2f(unsigned short h) {
  unsigned int u = ((unsigned int)h) << 16;
  return __builtin_bit_cast(float, u);
}

// packed f32->bf16 (RNE, same as f2b) — one instr for two values
__device__ __forceinline__ unsigned int pk_bf16(float a, float b) {
  unsigned int r;
  asm("v_cvt_pk_bf16_f32 %0, %1, %2" : "=v"(r) : "v"(a), "v"(b));
  return r;
}
// exchange a[32..63] <-> b[0..31]
__device__ __forceinline__ void plswap(unsigned int& a, unsigned int& b) {
  asm("v_permlane32_swap_b32 %0, %1" : "+v"(a), "+v"(b));
}

// ---------------- prep: convx + wconv_all fused (blockIdx split) ----------------
__global__ __launch_bounds__(256) void prep(const float* __restrict__ x,
                                            const float* __restrict__ Wq,
                                            const float* __restrict__ Wk,
                                            const float* __restrict__ Wv,
                                            const float* __restrict__ Wo,
                                            unsigned short* __restrict__ xb,
                                            unsigned short* __restrict__ WqkvT,
                                            unsigned short* __restrict__ WoT) {
  __shared__ float t[32][33];
  if (blockIdx.x < 4096) {
    int i = blockIdx.x * 256 + threadIdx.x;
    const float4* p = (const float4*)x + (size_t)i * 2;
    float4 a = p[0], b4 = p[1];
    union { short8 v; unsigned short u[8]; } o;
    o.u[0] = f2b(a.x);  o.u[1] = f2b(a.y);  o.u[2] = f2b(a.z);  o.u[3] = f2b(a.w);
    o.u[4] = f2b(b4.x); o.u[5] = f2b(b4.y); o.u[6] = f2b(b4.z); o.u[7] = f2b(b4.w);
    ((short8*)xb)[i] = o.v;
    return;
  }
  int idx = blockIdx.x - 4096;
  const float* W; unsigned short* WT; int N, tx, ty;
  const int K = 2048;
  if (idx < 4096)      { W = Wq; WT = WqkvT;                         N = 2048; idx -= 0;    tx = idx & 63; ty = idx >> 6; }
  else if (idx < 5120) { W = Wk; WT = WqkvT + (size_t)2048 * 2048;   N = 512;  idx -= 4096; tx = idx & 15; ty = idx >> 4; }
  else if (idx < 6144) { W = Wv; WT = WqkvT + (size_t)2560 * 2048;   N = 512;  idx -= 5120; tx = idx & 15; ty = idx >> 4; }
  else                 { W = Wo; WT = WoT;                           N = 2048; idx -= 6144; tx = idx & 63; ty = idx >> 6; }
  int c = threadIdx.x & 31, r0 = threadIdx.x >> 5;
  int k0 = ty * 32, n0 = tx * 32;
#pragma unroll
  for (int r = r0; r < 32; r += 8) t[r][c] = W[(size_t)(k0 + r) * N + n0 + c];
  __syncthreads();
#pragma unroll
  for (int r = r0; r < 32; r += 8) WT[(size_t)(n0 + r) * K + k0 + c] = f2b(t[c][r]);
}

// ---- shared K-loop machinery: 128x128 tile, BK=32, 4-deep, counted vmcnt ----
// Staging: per wave 32 A rows + 32 B rows; per instr 16 rows (64 lanes x 16B).
// Physical 16B chunk p of row r holds logical chunk p^(r&3).
// 4 loads/thread/tile -> steady-state 12 outstanding; wait vmcnt(8) = tile j.
#define GQ_STAGE(J, BUF)                                                      \
  { int kb_ = (J) * 32;                                                       \
    _Pragma("unroll") for (int i = 0; i < 2; ++i) {                           \
      int row = w * 32 + i * 16 + (lane >> 2);                                \
      int gc = (lane & 3) ^ (row & 3);                                        \
      async16(Ab + (size_t)row * K + kb_ + gc * 8,                            \
              &As[BUF][(w * 32 + i * 16) * 32]);                              \
      async16(Bb + (size_t)row * K + kb_ + gc * 8,                            \
              &Bs[BUF][(w * 32 + i * 16) * 32]); } }

#define GQ_COMPUTE(CUR)                                                       \
  { const unsigned short* as_ = &As[CUR][0];                                  \
    const unsigned short* bs_ = &Bs[CUR][0];                                  \
    short8 af[4], bfv[4];                                                     \
    _Pragma("unroll") for (int mi = 0; mi < 4; ++mi) {                        \
      int row = wm * 64 + mi * 16 + l15;                                      \
      af[mi] = *(const short8*)&as_[row * 32 + ((quad ^ (row & 3)) * 8)]; }   \
    _Pragma("unroll") for (int ni = 0; ni < 4; ++ni) {                        \
      int row = wn * 64 + ni * 16 + l15;                                      \
      bfv[ni] = *(const short8*)&bs_[row * 32 + ((quad ^ (row & 3)) * 8)]; }  \
    _Pragma("unroll") for (int mi = 0; mi < 4; ++mi)                          \
      _Pragma("unroll") for (int ni = 0; ni < 4; ++ni)                        \
        acc[mi][ni] = __builtin_amdgcn_mfma_f32_16x16x32_bf16(                \
            af[mi], bfv[ni], acc[mi][ni], 0, 0, 0); }

#define GQ_LOOP                                                               \
  GQ_STAGE(0, 0); GQ_STAGE(1, 1); GQ_STAGE(2, 2);                             \
  const int nIter = K >> 5;                                                   \
  for (int j = 0; j < nIter; ++j) {                                           \
    if (j + 2 < nIter) wait_vm8();                                            \
    else if (j + 1 < nIter) wait_vm4();                                       \
    else wait_vm0();                                                          \
    barrier_raw();                                                            \
    if (j + 3 < nIter) GQ_STAGE(j + 3, (j + 3) & 3);                          \
    GQ_COMPUTE(j & 3);                                                        \
  }

// ---------------- GEMM (plain): C[M,N] = A[M,K] * BT[N,K]^T ----------------
__global__ __launch_bounds__(256) void gemm_bt(const unsigned short* __restrict__ A,
                                               const unsigned short* __restrict__ BT,
                                               void* __restrict__ Cout,
                                               int M, int N, int K, int out_bf16) {
  const int n0 = blockIdx.x * 128;
  const int m0 = blockIdx.y * 128;
  const int tid = threadIdx.x;
  const int w = tid >> 6, lane = tid & 63, l15 = lane & 15, quad = lane >> 4;
  const int wm = w >> 1, wn = w & 1;

  __shared__ __align__(16) unsigned short As[4][128 * 32];
  __shared__ __align__(16) unsigned short Bs[4][128 * 32];

  f32x4 acc[4][4];
#pragma unroll
  for (int mi = 0; mi < 4; mi++)
#pragma unroll
    for (int ni = 0; ni < 4; ni++) acc[mi][ni] = (f32x4){0.f, 0.f, 0.f, 0.f};

  const unsigned short* Ab = A + (size_t)m0 * K;
  const unsigned short* Bb = BT + (size_t)n0 * K;

  GQ_LOOP

  if (out_bf16) {
    unsigned short* C = (unsigned short*)Cout;
#pragma unroll
    for (int mi = 0; mi < 4; mi++)
#pragma unroll
      for (int ni = 0; ni < 4; ni++)
#pragma unroll
        for (int r = 0; r < 4; r++) {
          int row = m0 + wm * 64 + mi * 16 + quad * 4 + r;
          int col = n0 + wn * 64 + ni * 16 + l15;
          C[(size_t)row * N + col] = f2b(acc[mi][ni][r]);
        }
  } else {
    float* C = (float*)Cout;
#pragma unroll
    for (int mi = 0; mi < 4; mi++)
#pragma unroll
      for (int ni = 0; ni < 4; ni++)
#pragma unroll
        for (int r = 0; r < 4; r++) {
          int row = m0 + wm * 64 + mi * 16 + quad * 4 + r;
          int col = n0 + wn * 64 + ni * 16 + l15;
          C[(size_t)row * N + col] = acc[mi][ni][r];
        }
  }
}

// ---------------- GEMM with fused RoPE / V-transpose epilogue ----------------
#define SC_TOT 0.12753785056274918f
__global__ __launch_bounds__(256) void gemm_qkv(const unsigned short* __restrict__ A,
                                                const unsigned short* __restrict__ BT,
                                                unsigned short* __restrict__ Qm,
                                                unsigned short* __restrict__ Km,
                                                unsigned short* __restrict__ Vtm) {
  const int K = 2048;
  const int n0 = blockIdx.x * 128;
  const int m0 = blockIdx.y * 128;
  const int tid = threadIdx.x;
  const int w = tid >> 6, lane = tid & 63, l15 = lane & 15, quad = lane >> 4;
  const int wm = w >> 1, wn = w & 1;

  // 64KB overlay: main loop As/Bs (32KB each); epilogue reuses as f32 L[128][128]
  __shared__ __align__(16) unsigned char smem[65536];
  unsigned short (*As)[128 * 32] = (unsigned short (*)[128 * 32])smem;
  unsigned short (*Bs)[128 * 32] = (unsigned short (*)[128 * 32])(smem + 32768);
  float* L = (float*)smem;

  f32x4 acc[4][4];
#pragma unroll
  for (int mi = 0; mi < 4; mi++)
#pragma unroll
    for (int ni = 0; ni < 4; ni++) acc[mi][ni] = (f32x4){0.f, 0.f, 0.f, 0.f};

  const unsigned short* Ab = A + (size_t)m0 * K;
  const unsigned short* Bb = BT + (size_t)n0 * K;

  GQ_LOOP

  // ---- fused epilogue ----
  __syncthreads();   // all waves done with As/Bs; no DMA outstanding after last iter
#pragma unroll
  for (int mi = 0; mi < 4; mi++)
#pragma unroll
    for (int ni = 0; ni < 4; ni++)
#pragma unroll
      for (int r = 0; r < 4; r++) {
        int rr = wm * 64 + mi * 16 + quad * 4 + r;
        int cc = wn * 64 + ni * 16 + l15;
        L[rr * 128 + (cc ^ (rr & 31))] = acc[mi][ni][r];
      }
  __syncthreads();

  const int head = blockIdx.x;       // one head per N-tile
  const int b = m0 >> 11;            // 2048 rows per batch
  const int s_base = m0 & 2047;

  if (head < 20) {                   // Q (0..15) / K (16..19): RoPE
    const int d = tid & 63, sl = tid >> 6;
    const bool isQ = head < 16;
    unsigned short* dq = isQ
      ? Qm + ((size_t)((b * 16 + head) * 2048 + s_base)) * 128
      : Km + ((size_t)((b * 4 + (head - 16)) * 2048 + s_base)) * 128;
    const float invf = exp2f(-0.20762050593046f * (float)d);
#pragma unroll 4
    for (int i = 0; i < 32; i++) {
      int s = sl + i * 4;
      // round-trip through bf16 to reproduce the old qkv(bf16)->rope numerics
      float lo = b2f(f2b(L[s * 128 + (d ^ (s & 31))]));
      float hi = b2f(f2b(L[s * 128 + ((d + 64) ^ (s & 31))]));
      float ang = (float)(s_base + s) * invf;
      float sn, cs;
      sincosf(ang, &sn, &cs);
      float nlo = lo * cs - hi * sn;
      float nhi = hi * cs + lo * sn;
      if (isQ) { nlo *= SC_TOT; nhi *= SC_TOT; }
      dq[(size_t)s * 128 + d]      = f2b(nlo);
      dq[(size_t)s * 128 + d + 64] = f2b(nhi);
    }
  } else {                           // V (20..23): transpose to Vt[b,kv,d,s]
    const int kv = head - 20;
    const int s_l = tid & 63, dl = tid >> 6;
    unsigned short* dv = Vtm + ((size_t)(b * 4 + kv) * 128) * 2048;
#pragma unroll 2
    for (int sh = 0; sh < 2; sh++) {
      int s = sh * 64 + s_l;
#pragma unroll 4
      for (int i = 0; i < 32; i++) {
        int d = i * 4 + dl;
        dv[(size_t)d * 2048 + s_base + s] = f2b(L[s * 128 + (d ^ (s & 31))]);
      }
    }
  }
}

// ---------------- Flash attention: split-KV wave groups ----------------
#define FIXED_M 12.0f

__device__ __forceinline__ void proc_acc(const f32x16& s, bool msk, int kvb, int q,
                                         float& l_own, short8& paL, short8& paH) {
  float p[16];
#pragma unroll
  for (int r = 0; r < 16; r++) {
    float v = exp2f(s[r] - FIXED_M);
    if (msk) {
      int kv = kvb + (r & 3) + 8 * (r >> 2);
      if (kv > q) v = 0.f;
    }
    p[r] = v;
    l_own += v;
  }
  unsigned int u0 = pk_bf16(p[0], p[1]),  u1 = pk_bf16(p[2], p[3]);
  unsigned int u2 = pk_bf16(p[4], p[5]),  u3 = pk_bf16(p[6], p[7]);
  plswap(u0, u2); plswap(u1, u3);
  unsigned int w0 = pk_bf16(p[8], p[9]),  w1 = pk_bf16(p[10], p[11]);
  unsigned int w2 = pk_bf16(p[12], p[13]), w3 = pk_bf16(p[14], p[15]);
  plswap(w0, w2); plswap(w1, w3);
  union { unsigned int u[4]; short8 s8; } a, b;
  a.u[0] = u0; a.u[1] = u1; a.u[2] = u2; a.u[3] = u3;
  b.u[0] = w0; b.u[1] = w1; b.u[2] = w2; b.u[3] = w3;
  paL = a.s8; paH = b.s8;
}

// 512 threads = 2 wave-groups of 4 waves. Group g handles KV tiles
// [g*(qt+1), (g+1)*(qt+1)) of q-tile qt. Fixed-max softmax => group partials
// combine by addition of O and l. Paired q-tiles (pair, 15-pair) => every
// block/group runs exactly 17 lockstep KV tiles. All o[] indices static
// (rule #20) — epilogue branches on wave-uniform g.
__global__ __launch_bounds__(512, 2) void flash2(const unsigned short* __restrict__ Q,
                                                 const unsigned short* __restrict__ Kc,
                                                 const unsigned short* __restrict__ Vt,
                                                 unsigned short* __restrict__ attn) {
  const int pair = blockIdx.x;         // 0..7
  const int h = blockIdx.y;
  const int b = blockIdx.z;
  const int kvh = h >> 2;
  const int tid = threadIdx.x;
  const int w = tid >> 6;              // 0..7
  const int g = w >> 2;                // KV-half group
  const int wg = w & 3;                // wave within group
  const int lane = tid & 63;
  const int l31 = lane & 31, hi = lane >> 5, x7 = l31 & 7;

  __shared__ __align__(16) unsigned short kbuf[2][2][64 * 128];  // [group][buf]
  __shared__ __align__(16) unsigned short vbuf[2][2][128 * 64];  // [group][buf]
  __shared__ float lx[2][4][32];       // per-group partial l
  __shared__ float li[2][4][32];       // per-group 1/l_tot

  const unsigned short* Qb = Q  + ((size_t)(b * 16 + h)) * 2048 * 128;
  const unsigned short* Kb = Kc + ((size_t)(b * 4 + kvh)) * 2048 * 128;
  const unsigned short* Vb = Vt + ((size_t)(b * 4 + kvh)) * 128 * 2048;

  for (int t = 0; t < 2; t++) {
    const int qt = (t == 0) ? pair : (15 - pair);
    const int q0 = qt * 128;
    const int qw = q0 + wg * 32;       // wave's q base (32 rows)
    const int qv = qw + l31;           // this lane's q row
    const int half = qt + 1;           // KV tiles per group
    const int j0 = g * half;           // group's first KV tile

    // Q fragments: qf[s] = Q[qv][s*16 + hi*8 .. +7]
    short8 qf[8];
    {
      const unsigned short* qp = Qb + (size_t)qv * 128 + hi * 8;
#pragma unroll
      for (int s = 0; s < 8; s++) qf[s] = *(const short8*)(qp + s * 16);
    }

    f32x16 o[4];
#pragma unroll
    for (int d = 0; d < 4; d++)
#pragma unroll
      for (int e = 0; e < 16; e++) o[d][e] = 0.f;
    float l_own = 0.f;

    __syncthreads();                   // prev pass LDS fully consumed

    // prologue: DMA group's tile j0 into buf 0
#pragma unroll
    for (int k2 = 0; k2 < 4; k2++) {
      int m = wg * 4 + k2;
      int rl = m * 4 + (lane >> 4);
      int c8 = (lane & 15) ^ (rl & 7);
      async16(Kb + (size_t)(j0 * 64 + rl) * 128 + c8 * 8, &kbuf[g][0][m * 512]);
    }
#pragma unroll
    for (int k2 = 0; k2 < 4; k2++) {
      int m = wg * 4 + k2;
      int d = m * 8 + (lane >> 3);
      int c3 = (lane & 7) ^ (d & 7);
      async16(Vb + (size_t)d * 2048 + j0 * 64 + c3 * 8, &vbuf[g][0][m * 512]);
    }

    for (int i = 0; i < half; i++) {
      wait_vm0();
      barrier_raw();
      const int cur = i & 1;
      const int kb = (j0 + i) * 64;

      if (i + 1 < half) {
        int kb2 = kb + 64;
#pragma unroll
        for (int k2 = 0; k2 < 4; k2++) {
          int m = wg * 4 + k2;
          int rl = m * 4 + (lane >> 4);
          int c8 = (lane & 15) ^ (rl & 7);
          async16(Kb + (size_t)(kb2 + rl) * 128 + c8 * 8, &kbuf[g][cur ^ 1][m * 512]);
        }
#pragma unroll
        for (int k2 = 0; k2 < 4; k2++) {
          int m = wg * 4 + k2;
          int d = m * 8 + (lane >> 3);
          int c3 = (lane & 7) ^ (d & 7);
          async16(Vb + (size_t)d * 2048 + kb2 + c3 * 8, &vbuf[g][cur ^ 1][m * 512]);
        }
      }

      if (kb <= qw + 31) {             // tile not fully above diagonal
        // QK^T swapped: S^T[kv, q] = mfma(A=K, B=Q), two 32-kv blocks
        f32x16 sA, sB;
#pragma unroll
        for (int e = 0; e < 16; e++) { sA[e] = 0.f; sB[e] = 0.f; }
        const unsigned short* kp = &kbuf[g][cur][0];
        __builtin_amdgcn_s_setprio(1);
#pragma unroll
        for (int s = 0; s < 8; s++) {
          int ch = (((s << 1) | hi) ^ x7) << 3;
          short8 ka = *(const short8*)&kp[l31 * 128 + ch];
          short8 kB2 = *(const short8*)&kp[(32 + l31) * 128 + ch];
          sA = __builtin_amdgcn_mfma_f32_32x32x16_bf16(ka, qf[s], sA, 0, 0, 0);
          sB = __builtin_amdgcn_mfma_f32_32x32x16_bf16(kB2, qf[s], sB, 0, 0, 0);
        }
        __builtin_amdgcn_s_setprio(0);

        const bool msk = (kb + 63 > qw);
        short8 pa[4];
        proc_acc(sA, msk, kb + 4 * hi, qv, l_own, pa[0], pa[1]);
        proc_acc(sB, msk, kb + 32 + 4 * hi, qv, l_own, pa[2], pa[3]);

        // PV: O[q, d] += P * V
        const unsigned short* vp = &vbuf[g][cur][0];
        __builtin_amdgcn_s_setprio(1);
#pragma unroll
        for (int db = 0; db < 4; db++) {
          int ro = (db * 32 + l31) * 64;
#pragma unroll
          for (int f = 0; f < 4; f++) {
            int ch = (((f << 1) | hi) ^ x7) << 3;
            short8 vf = *(const short8*)&vp[ro + ch];
            o[db] = __builtin_amdgcn_mfma_f32_32x32x16_bf16(pa[f], vf, o[db], 0, 0, 0);
          }
        }
        __builtin_amdgcn_s_setprio(0);
      }
    }

    // ---- combine group partials (fixed-max: O and l just add) ----
    __syncthreads();                   // compute done; kbufs free as scratch
    {
      float* wout = (float*)&kbuf[g ^ 1][0][0];
      float lown = l_own + __shfl_xor(l_own, 32);
      if (hi == 0) lx[g][wg][l31] = lown;
      const int base = wg * 2048 + lane * 4;
      if (g == 0) {                    // g0 sends db 2,3
#pragma unroll
        for (int r4 = 0; r4 < 4; r4++) {
          *(f32x4*)&wout[base + 0 * 1024 + r4 * 256] =
            (f32x4){ o[2][r4 * 4 + 0], o[2][r4 * 4 + 1], o[2][r4 * 4 + 2], o[2][r4 * 4 + 3] };
          *(f32x4*)&wout[base + 1 * 1024 + r4 * 256] =
            (f32x4){ o[3][r4 * 4 + 0], o[3][r4 * 4 + 1], o[3][r4 * 4 + 2], o[3][r4 * 4 + 3] };
        }
      } else {                         // g1 sends db 0,1
#pragma unroll
        for (int r4 = 0; r4 < 4; r4++) {
          *(f32x4*)&wout[base + 0 * 1024 + r4 * 256] =
            (f32x4){ o[0][r4 * 4 + 0], o[0][r4 * 4 + 1], o[0][r4 * 4 + 2], o[0][r4 * 4 + 3] };
          *(f32x4*)&wout[base + 1 * 1024 + r4 * 256] =
            (f32x4){ o[1][r4 * 4 + 0], o[1][r4 * 4 + 1], o[1][r4 * 4 + 2], o[1][r4 * 4 + 3] };
        }
      }
      __syncthreads();
      const float* rin = (const float*)&kbuf[g][0][0];
      float ltot = lown + lx[g ^ 1][wg][l31];
      if (hi == 0) li[g][wg][l31] = 1.f / ltot;
      f32x4 inv4[4];
#pragma unroll
      for (int tt = 0; tt < 4; tt++) inv4[tt] = *(const f32x4*)&li[g][wg][tt * 8 + 4 * hi];

      // O C-layout: col(lane)=d=db*32+l31, row(reg)=(r&3)+8*(r>>2)+4*hi
      unsigned short* ap0 = attn + ((size_t)(b * 2048 + qw)) * 2048 + h * 128 + l31;
      if (g == 0) {                    // g0 keeps db 0,1 -> cols 0,32
#pragma unroll
        for (int r4 = 0; r4 < 4; r4++) {
          f32x4 v0 = *(const f32x4*)&rin[base + 0 * 1024 + r4 * 256];
          f32x4 v1 = *(const f32x4*)&rin[base + 1 * 1024 + r4 * 256];
#pragma unroll
          for (int k = 0; k < 4; k++) {
            o[0][r4 * 4 + k] += v0[k];
            o[1][r4 * 4 + k] += v1[k];
          }
        }
#pragma unroll
        for (int r = 0; r < 16; r++) {
          int rowq = (r & 3) + 8 * (r >> 2) + 4 * hi;
          float iv = inv4[r >> 2][r & 3];
          ap0[(size_t)rowq * 2048 + 0]  = f2b(o[0][r] * iv);
          ap0[(size_t)rowq * 2048 + 32] = f2b(o[1][r] * iv);
        }
      } else {                         // g1 keeps db 2,3 -> cols 64,96
#pragma unroll
        for (int r4 = 0; r4 < 4; r4++) {
          f32x4 v0 = *(const f32x4*)&rin[base + 0 * 1024 + r4 * 256];
          f32x4 v1 = *(const f32x4*)&rin[base + 1 * 1024 + r4 * 256];
#pragma unroll
          for (int k = 0; k < 4; k++) {
            o[2][r4 * 4 + k] += v0[k];
            o[3][r4 * 4 + k] += v1[k];
          }
        }
#pragma unroll
        for (int r = 0; r < 16; r++) {
          int rowq = (r & 3) + 8 * (r >> 2) + 4 * hi;
          float iv = inv4[r >> 2][r & 3];
          ap0[(size_t)rowq * 2048 + 64] = f2b(o[2][r] * iv);
          ap0[(size_t)rowq * 2048 + 96] = f2b(o[3][r] * iv);
        }
      }
    }
  }
}

// ---------------------------------------------------------------------------
extern "C" void kernel_launch(void* const* d_in, const int* in_sizes, int n_in,
                              void* d_out, int out_size, void* d_ws, size_t ws_size,
                              hipStream_t stream) {
  const float* x  = (const float*)d_in[0];
  const float* Wq = (const float*)d_in[1];
  const float* Wk = (const float*)d_in[2];
  const float* Wv = (const float*)d_in[3];
  const float* Wo = (const float*)d_in[4];
  float* out = (float*)d_out;

  char* ws = (char*)d_ws;
  unsigned short* xb    = (unsigned short*)(ws);              // 16.78 MB (reused as attn)
  unsigned short* WqkvT = (unsigned short*)(ws + 16777216);   // 12.58 MB [3072][2048]
  unsigned short* WoT   = (unsigned short*)(ws + 29360128);   //  8.39 MB [2048][2048]
  unsigned short* Qm    = (unsigned short*)(ws + 62914560);   // 16.78 MB [B,H,S,D]
  unsigned short* Km    = (unsigned short*)(ws + 79691776);   //  4.19 MB [B,KV,S,D]
  unsigned short* Vtm   = (unsigned short*)(ws + 83886080);   //  4.19 MB [B,KV,D,S]
  unsigned short* attn  = xb;

  prep<<<14336, 256, 0, stream>>>(x, Wq, Wk, Wv, Wo, xb, WqkvT, WoT);

  gemm_qkv<<<dim3(24, 32), 256, 0, stream>>>(xb, WqkvT, Qm, Km, Vtm);

  flash2<<<dim3(8, 16, 2), 512, 0, stream>>>(Qm, Km, Vtm, attn);

  gemm_bt<<<dim3(16, 32), 256, 0, stream>>>(attn, WoT, out, 4096, 2048, 2048, 0);
}

// Round 8
// 295.584 us; speedup vs baseline: 1.0427x; 1.0427x over previous
//
#include <hip/hip_runtime.h>
#include <math.h>

// ---------------------------------------------------------------------------
// ByteMultiHeadSelfAttention: B=2 S=2048 E=2048, H=16 KV=4 D=128, RoPE, causal.
// 4 launches:
//   prep:      convx (x fp32 -> xb bf16) + wconv (W -> W^T bf16), fused
//   gemm_qkv:  qkv = xb @ Wqkv, 128x128 tile, BK=32, 3-deep DMA pipeline with
//              counted vmcnt, conflict-free swizzle f(r)=(r>>1)&3, 48KB LDS
//              (3 blocks/CU) + FUSED epilogue: RoPE -> Qm/Km, V^T -> Vtm
//   flash2:    512 threads; 2 wave-groups split-KV (fixed-max softmax => adds),
//              32x32 MFMA, swapped QK^T, in-register P, paired q-tiles
//   gemm_bt:   out = attn @ Wo (fp32), same 3-deep pipeline
// ---------------------------------------------------------------------------

typedef __attribute__((ext_vector_type(8))) short short8;
typedef __attribute__((ext_vector_type(4))) float f32x4;
typedef __attribute__((ext_vector_type(16))) float f32x16;

typedef const __attribute__((address_space(1))) void* gvp;
typedef __attribute__((address_space(3))) void* svp;

__device__ __forceinline__ void async16(const void* g, void* l) {
  __builtin_amdgcn_global_load_lds((gvp)g, (svp)l, 16, 0, 0);
}
__device__ __forceinline__ void wait_vm0() { asm volatile("s_waitcnt vmcnt(0)" ::: "memory"); }
__device__ __forceinline__ void wait_vm4() { asm volatile("s_waitcnt vmcnt(4)" ::: "memory"); }
__device__ __forceinline__ void barrier_raw() { asm volatile("s_barrier" ::: "memory"); }

__device__ __forceinline__ unsigned short f2b(float f) {
  unsigned int u = __builtin_bit_cast(unsigned int, f);
  u += 0x7fffu + ((u >> 16) & 1u);   // RNE
  return (unsigned short)(u >> 16);
}
__device__ __forceinline__ float b2f(unsigned short h) {
  unsigned int u = ((unsigned int)h) << 16;
  return __builtin_bit_cast(float, u);
}

// packed f32->bf16 (RNE, same as f2b) — one instr for two values
__device__ __forceinline__ unsigned int pk_bf16(float a, float b) {
  unsigned int r;
  asm("v_cvt_pk_bf16_f32 %0, %1, %2" : "=v"(r) : "v"(a), "v"(b));
  return r;
}
// exchange a[32..63] <-> b[0..31]
__device__ __forceinline__ void plswap(unsigned int& a, unsigned int& b) {
  asm("v_permlane32_swap_b32 %0, %1" : "+v"(a), "+v"(b));
}

// ---------------- prep: convx + wconv_all fused (blockIdx split) ----------------
__global__ __launch_bounds__(256) void prep(const float* __restrict__ x,
                                            const float* __restrict__ Wq,
                                            const float* __restrict__ Wk,
                                            const float* __restrict__ Wv,
                                            const float* __restrict__ Wo,
                                            unsigned short* __restrict__ xb,
                                            unsigned short* __restrict__ WqkvT,
                                            unsigned short* __restrict__ WoT) {
  __shared__ float t[32][33];
  if (blockIdx.x < 4096) {
    int i = blockIdx.x * 256 + threadIdx.x;
    const float4* p = (const float4*)x + (size_t)i * 2;
    float4 a = p[0], b4 = p[1];
    union { short8 v; unsigned short u[8]; } o;
    o.u[0] = f2b(a.x);  o.u[1] = f2b(a.y);  o.u[2] = f2b(a.z);  o.u[3] = f2b(a.w);
    o.u[4] = f2b(b4.x); o.u[5] = f2b(b4.y); o.u[6] = f2b(b4.z); o.u[7] = f2b(b4.w);
    ((short8*)xb)[i] = o.v;
    return;
  }
  int idx = blockIdx.x - 4096;
  const float* W; unsigned short* WT; int N, tx, ty;
  const int K = 2048;
  if (idx < 4096)      { W = Wq; WT = WqkvT;                         N = 2048; idx -= 0;    tx = idx & 63; ty = idx >> 6; }
  else if (idx < 5120) { W = Wk; WT = WqkvT + (size_t)2048 * 2048;   N = 512;  idx -= 4096; tx = idx & 15; ty = idx >> 4; }
  else if (idx < 6144) { W = Wv; WT = WqkvT + (size_t)2560 * 2048;   N = 512;  idx -= 5120; tx = idx & 15; ty = idx >> 4; }
  else                 { W = Wo; WT = WoT;                           N = 2048; idx -= 6144; tx = idx & 63; ty = idx >> 6; }
  int c = threadIdx.x & 31, r0 = threadIdx.x >> 5;
  int k0 = ty * 32, n0 = tx * 32;
#pragma unroll
  for (int r = r0; r < 32; r += 8) t[r][c] = W[(size_t)(k0 + r) * N + n0 + c];
  __syncthreads();
#pragma unroll
  for (int r = r0; r < 32; r += 8) WT[(size_t)(n0 + r) * K + k0 + c] = f2b(t[c][r]);
}

// ---- shared K-loop: 128x128 tile, BK=32, 3-deep pipeline, counted vmcnt ----
// Staging: 4 loads/thread/tile; physical 16B chunk p of row r holds logical
// chunk p^((r>>1)&3). Read (16 lanes, same quad): bank slot = (r&1, chunk)
// -> 8 slots x 2 lanes = 2-way = free (m136).
// Pipeline: stage j+2 each iter; vmcnt(4) waits tile j only (tile j+1 in
// flight across the barrier) -> ~2 compute phases of latency slack.
#define GQ_STAGE(J, BUF)                                                      \
  { int kb_ = (J) * 32;                                                       \
    _Pragma("unroll") for (int i = 0; i < 2; ++i) {                           \
      int row = w * 32 + i * 16 + (lane >> 2);                                \
      int gc = (lane & 3) ^ ((row >> 1) & 3);                                 \
      async16(Ab + (size_t)row * K + kb_ + gc * 8,                            \
              &As[BUF][(w * 32 + i * 16) * 32]);                              \
      async16(Bb + (size_t)row * K + kb_ + gc * 8,                            \
              &Bs[BUF][(w * 32 + i * 16) * 32]); } }

#define GQ_COMPUTE(CUR)                                                       \
  { const unsigned short* as_ = &As[CUR][0];                                  \
    const unsigned short* bs_ = &Bs[CUR][0];                                  \
    short8 af[4], bfv[4];                                                     \
    _Pragma("unroll") for (int mi = 0; mi < 4; ++mi) {                        \
      int row = wm * 64 + mi * 16 + l15;                                      \
      af[mi] = *(const short8*)&as_[row * 32 + ((quad ^ ((row >> 1) & 3)) * 8)]; } \
    _Pragma("unroll") for (int ni = 0; ni < 4; ++ni) {                        \
      int row = wn * 64 + ni * 16 + l15;                                      \
      bfv[ni] = *(const short8*)&bs_[row * 32 + ((quad ^ ((row >> 1) & 3)) * 8)]; } \
    _Pragma("unroll") for (int mi = 0; mi < 4; ++mi)                          \
      _Pragma("unroll") for (int ni = 0; ni < 4; ++ni)                        \
        acc[mi][ni] = __builtin_amdgcn_mfma_f32_16x16x32_bf16(                \
            af[mi], bfv[ni], acc[mi][ni], 0, 0, 0); }

#define GQ_LOOP                                                               \
  GQ_STAGE(0, 0); GQ_STAGE(1, 1);                                             \
  const int nIter = K >> 5;                                                   \
  { int c3 = 0, s3 = 2;                                                       \
    for (int j = 0; j < nIter; ++j) {                                         \
      if (j + 1 < nIter) wait_vm4(); else wait_vm0();                         \
      barrier_raw();                                                          \
      if (j + 2 < nIter) GQ_STAGE(j + 2, s3);                                 \
      GQ_COMPUTE(c3);                                                         \
      c3 = (c3 == 2) ? 0 : c3 + 1;                                            \
      s3 = (s3 == 2) ? 0 : s3 + 1;                                            \
    } }

// ---------------- GEMM (plain): C[M,N] = A[M,K] * BT[N,K]^T ----------------
__global__ __launch_bounds__(256, 3) void gemm_bt(const unsigned short* __restrict__ A,
                                                  const unsigned short* __restrict__ BT,
                                                  void* __restrict__ Cout,
                                                  int M, int N, int K, int out_bf16) {
  const int n0 = blockIdx.x * 128;
  const int m0 = blockIdx.y * 128;
  const int tid = threadIdx.x;
  const int w = tid >> 6, lane = tid & 63, l15 = lane & 15, quad = lane >> 4;
  const int wm = w >> 1, wn = w & 1;

  __shared__ __align__(16) unsigned short As[3][128 * 32];
  __shared__ __align__(16) unsigned short Bs[3][128 * 32];

  f32x4 acc[4][4];
#pragma unroll
  for (int mi = 0; mi < 4; mi++)
#pragma unroll
    for (int ni = 0; ni < 4; ni++) acc[mi][ni] = (f32x4){0.f, 0.f, 0.f, 0.f};

  const unsigned short* Ab = A + (size_t)m0 * K;
  const unsigned short* Bb = BT + (size_t)n0 * K;

  GQ_LOOP

  if (out_bf16) {
    unsigned short* C = (unsigned short*)Cout;
#pragma unroll
    for (int mi = 0; mi < 4; mi++)
#pragma unroll
      for (int ni = 0; ni < 4; ni++)
#pragma unroll
        for (int r = 0; r < 4; r++) {
          int row = m0 + wm * 64 + mi * 16 + quad * 4 + r;
          int col = n0 + wn * 64 + ni * 16 + l15;
          C[(size_t)row * N + col] = f2b(acc[mi][ni][r]);
        }
  } else {
    float* C = (float*)Cout;
#pragma unroll
    for (int mi = 0; mi < 4; mi++)
#pragma unroll
      for (int ni = 0; ni < 4; ni++)
#pragma unroll
        for (int r = 0; r < 4; r++) {
          int row = m0 + wm * 64 + mi * 16 + quad * 4 + r;
          int col = n0 + wn * 64 + ni * 16 + l15;
          C[(size_t)row * N + col] = acc[mi][ni][r];
        }
  }
}

// ---------------- GEMM with fused RoPE / V-transpose epilogue ----------------
// Epilogue stages the 128x128 tile as bf16 in padded LDS L[128][130] (33KB,
// fits the 48KB staging envelope -> 3 blocks/CU). bf16 staging is bit-identical
// to the old qkv(bf16) intermediate: rope read b2f(f2b(acc)), vtrans copied
// f2b(acc).
#define SC_TOT 0.12753785056274918f
__global__ __launch_bounds__(256, 3) void gemm_qkv(const unsigned short* __restrict__ A,
                                                   const unsigned short* __restrict__ BT,
                                                   unsigned short* __restrict__ Qm,
                                                   unsigned short* __restrict__ Km,
                                                   unsigned short* __restrict__ Vtm) {
  const int K = 2048;
  const int n0 = blockIdx.x * 128;
  const int m0 = blockIdx.y * 128;
  const int tid = threadIdx.x;
  const int w = tid >> 6, lane = tid & 63, l15 = lane & 15, quad = lane >> 4;
  const int wm = w >> 1, wn = w & 1;

  // 48KB overlay: main loop As/Bs (24KB each); epilogue reuses as bf16 L[128][130]
  __shared__ __align__(16) unsigned char smem[49152];
  unsigned short (*As)[128 * 32] = (unsigned short (*)[128 * 32])smem;
  unsigned short (*Bs)[128 * 32] = (unsigned short (*)[128 * 32])(smem + 24576);
  unsigned short* L = (unsigned short*)smem;   // [128][130] bf16, padded

  f32x4 acc[4][4];
#pragma unroll
  for (int mi = 0; mi < 4; mi++)
#pragma unroll
    for (int ni = 0; ni < 4; ni++) acc[mi][ni] = (f32x4){0.f, 0.f, 0.f, 0.f};

  const unsigned short* Ab = A + (size_t)m0 * K;
  const unsigned short* Bb = BT + (size_t)n0 * K;

  GQ_LOOP

  // ---- fused epilogue ----
  __syncthreads();   // all waves done with As/Bs; all DMA drained (last iter vm0)
#pragma unroll
  for (int mi = 0; mi < 4; mi++)
#pragma unroll
    for (int ni = 0; ni < 4; ni++)
#pragma unroll
      for (int r = 0; r < 4; r++) {
        int rr = wm * 64 + mi * 16 + quad * 4 + r;
        int cc = wn * 64 + ni * 16 + l15;
        L[rr * 130 + cc] = f2b(acc[mi][ni][r]);
      }
  __syncthreads();

  const int head = blockIdx.x;       // one head per N-tile
  const int b = m0 >> 11;            // 2048 rows per batch
  const int s_base = m0 & 2047;

  if (head < 20) {                   // Q (0..15) / K (16..19): RoPE
    const int d = tid & 63, sl = tid >> 6;
    const bool isQ = head < 16;
    unsigned short* dq = isQ
      ? Qm + ((size_t)((b * 16 + head) * 2048 + s_base)) * 128
      : Km + ((size_t)((b * 4 + (head - 16)) * 2048 + s_base)) * 128;
    const float invf = exp2f(-0.20762050593046f * (float)d);
#pragma unroll 4
    for (int i = 0; i < 32; i++) {
      int s = sl + i * 4;
      float lo = b2f(L[s * 130 + d]);
      float hi = b2f(L[s * 130 + d + 64]);
      float ang = (float)(s_base + s) * invf;
      float sn, cs;
      sincosf(ang, &sn, &cs);
      float nlo = lo * cs - hi * sn;
      float nhi = hi * cs + lo * sn;
      if (isQ) { nlo *= SC_TOT; nhi *= SC_TOT; }
      dq[(size_t)s * 128 + d]      = f2b(nlo);
      dq[(size_t)s * 128 + d + 64] = f2b(nhi);
    }
  } else {                           // V (20..23): transpose to Vt[b,kv,d,s]
    const int kv = head - 20;
    const int s_l = tid & 63, dl = tid >> 6;
    unsigned short* dv = Vtm + ((size_t)(b * 4 + kv) * 128) * 2048;
#pragma unroll 2
    for (int sh = 0; sh < 2; sh++) {
      int s = sh * 64 + s_l;
#pragma unroll 4
      for (int i = 0; i < 32; i++) {
        int d = i * 4 + dl;
        dv[(size_t)d * 2048 + s_base + s] = L[s * 130 + d];
      }
    }
  }
}

// ---------------- Flash attention: split-KV wave groups ----------------
#define FIXED_M 12.0f

__device__ __forceinline__ void proc_acc(const f32x16& s, bool msk, int kvb, int q,
                                         float& l_own, short8& paL, short8& paH) {
  float p[16];
#pragma unroll
  for (int r = 0; r < 16; r++) {
    float v = exp2f(s[r] - FIXED_M);
    if (msk) {
      int kv = kvb + (r & 3) + 8 * (r >> 2);
      if (kv > q) v = 0.f;
    }
    p[r] = v;
    l_own += v;
  }
  unsigned int u0 = pk_bf16(p[0], p[1]),  u1 = pk_bf16(p[2], p[3]);
  unsigned int u2 = pk_bf16(p[4], p[5]),  u3 = pk_bf16(p[6], p[7]);
  plswap(u0, u2); plswap(u1, u3);
  unsigned int w0 = pk_bf16(p[8], p[9]),  w1 = pk_bf16(p[10], p[11]);
  unsigned int w2 = pk_bf16(p[12], p[13]), w3 = pk_bf16(p[14], p[15]);
  plswap(w0, w2); plswap(w1, w3);
  union { unsigned int u[4]; short8 s8; } a, b;
  a.u[0] = u0; a.u[1] = u1; a.u[2] = u2; a.u[3] = u3;
  b.u[0] = w0; b.u[1] = w1; b.u[2] = w2; b.u[3] = w3;
  paL = a.s8; paH = b.s8;
}

// 512 threads = 2 wave-groups of 4 waves. Group g handles KV tiles
// [g*(qt+1), (g+1)*(qt+1)) of q-tile qt. Fixed-max softmax => group partials
// combine by addition of O and l. Paired q-tiles (pair, 15-pair) => every
// block/group runs exactly 17 lockstep KV tiles. All o[] indices static
// (rule #20) — epilogue branches on wave-uniform g.
__global__ __launch_bounds__(512, 2) void flash2(const unsigned short* __restrict__ Q,
                                                 const unsigned short* __restrict__ Kc,
                                                 const unsigned short* __restrict__ Vt,
                                                 unsigned short* __restrict__ attn) {
  const int pair = blockIdx.x;         // 0..7
  const int h = blockIdx.y;
  const int b = blockIdx.z;
  const int kvh = h >> 2;
  const int tid = threadIdx.x;
  const int w = tid >> 6;              // 0..7
  const int g = w >> 2;                // KV-half group
  const int wg = w & 3;                // wave within group
  const int lane = tid & 63;
  const int l31 = lane & 31, hi = lane >> 5, x7 = l31 & 7;

  __shared__ __align__(16) unsigned short kbuf[2][2][64 * 128];  // [group][buf]
  __shared__ __align__(16) unsigned short vbuf[2][2][128 * 64];  // [group][buf]
  __shared__ float lx[2][4][32];       // per-group partial l
  __shared__ float li[2][4][32];       // per-group 1/l_tot

  const unsigned short* Qb = Q  + ((size_t)(b * 16 + h)) * 2048 * 128;
  const unsigned short* Kb = Kc + ((size_t)(b * 4 + kvh)) * 2048 * 128;
  const unsigned short* Vb = Vt + ((size_t)(b * 4 + kvh)) * 128 * 2048;

  for (int t = 0; t < 2; t++) {
    const int qt = (t == 0) ? pair : (15 - pair);
    const int q0 = qt * 128;
    const int qw = q0 + wg * 32;       // wave's q base (32 rows)
    const int qv = qw + l31;           // this lane's q row
    const int half = qt + 1;           // KV tiles per group
    const int j0 = g * half;           // group's first KV tile

    // Q fragments: qf[s] = Q[qv][s*16 + hi*8 .. +7]
    short8 qf[8];
    {
      const unsigned short* qp = Qb + (size_t)qv * 128 + hi * 8;
#pragma unroll
      for (int s = 0; s < 8; s++) qf[s] = *(const short8*)(qp + s * 16);
    }

    f32x16 o[4];
#pragma unroll
    for (int d = 0; d < 4; d++)
#pragma unroll
      for (int e = 0; e < 16; e++) o[d][e] = 0.f;
    float l_own = 0.f;

    __syncthreads();                   // prev pass LDS fully consumed

    // prologue: DMA group's tile j0 into buf 0
#pragma unroll
    for (int k2 = 0; k2 < 4; k2++) {
      int m = wg * 4 + k2;
      int rl = m * 4 + (lane >> 4);
      int c8 = (lane & 15) ^ (rl & 7);
      async16(Kb + (size_t)(j0 * 64 + rl) * 128 + c8 * 8, &kbuf[g][0][m * 512]);
    }
#pragma unroll
    for (int k2 = 0; k2 < 4; k2++) {
      int m = wg * 4 + k2;
      int d = m * 8 + (lane >> 3);
      int c3 = (lane & 7) ^ (d & 7);
      async16(Vb + (size_t)d * 2048 + j0 * 64 + c3 * 8, &vbuf[g][0][m * 512]);
    }

    for (int i = 0; i < half; i++) {
      wait_vm0();
      barrier_raw();
      const int cur = i & 1;
      const int kb = (j0 + i) * 64;

      if (i + 1 < half) {
        int kb2 = kb + 64;
#pragma unroll
        for (int k2 = 0; k2 < 4; k2++) {
          int m = wg * 4 + k2;
          int rl = m * 4 + (lane >> 4);
          int c8 = (lane & 15) ^ (rl & 7);
          async16(Kb + (size_t)(kb2 + rl) * 128 + c8 * 8, &kbuf[g][cur ^ 1][m * 512]);
        }
#pragma unroll
        for (int k2 = 0; k2 < 4; k2++) {
          int m = wg * 4 + k2;
          int d = m * 8 + (lane >> 3);
          int c3 = (lane & 7) ^ (d & 7);
          async16(Vb + (size_t)d * 2048 + kb2 + c3 * 8, &vbuf[g][cur ^ 1][m * 512]);
        }
      }

      if (kb <= qw + 31) {             // tile not fully above diagonal
        // QK^T swapped: S^T[kv, q] = mfma(A=K, B=Q), two 32-kv blocks
        f32x16 sA, sB;
#pragma unroll
        for (int e = 0; e < 16; e++) { sA[e] = 0.f; sB[e] = 0.f; }
        const unsigned short* kp = &kbuf[g][cur][0];
        __builtin_amdgcn_s_setprio(1);
#pragma unroll
        for (int s = 0; s < 8; s++) {
          int ch = (((s << 1) | hi) ^ x7) << 3;
          short8 ka = *(const short8*)&kp[l31 * 128 + ch];
          short8 kB2 = *(const short8*)&kp[(32 + l31) * 128 + ch];
          sA = __builtin_amdgcn_mfma_f32_32x32x16_bf16(ka, qf[s], sA, 0, 0, 0);
          sB = __builtin_amdgcn_mfma_f32_32x32x16_bf16(kB2, qf[s], sB, 0, 0, 0);
        }
        __builtin_amdgcn_s_setprio(0);

        const bool msk = (kb + 63 > qw);
        short8 pa[4];
        proc_acc(sA, msk, kb + 4 * hi, qv, l_own, pa[0], pa[1]);
        proc_acc(sB, msk, kb + 32 + 4 * hi, qv, l_own, pa[2], pa[3]);

        // PV: O[q, d] += P * V
        const unsigned short* vp = &vbuf[g][cur][0];
        __builtin_amdgcn_s_setprio(1);
#pragma unroll
        for (int db = 0; db < 4; db++) {
          int ro = (db * 32 + l31) * 64;
#pragma unroll
          for (int f = 0; f < 4; f++) {
            int ch = (((f << 1) | hi) ^ x7) << 3;
            short8 vf = *(const short8*)&vp[ro + ch];
            o[db] = __builtin_amdgcn_mfma_f32_32x32x16_bf16(pa[f], vf, o[db], 0, 0, 0);
          }
        }
        __builtin_amdgcn_s_setprio(0);
      }
    }

    // ---- combine group partials (fixed-max: O and l just add) ----
    __syncthreads();                   // compute done; kbufs free as scratch
    {
      float* wout = (float*)&kbuf[g ^ 1][0][0];
      float lown = l_own + __shfl_xor(l_own, 32);
      if (hi == 0) lx[g][wg][l31] = lown;
      const int base = wg * 2048 + lane * 4;
      if (g == 0) {                    // g0 sends db 2,3
#pragma unroll
        for (int r4 = 0; r4 < 4; r4++) {
          *(f32x4*)&wout[base + 0 * 1024 + r4 * 256] =
            (f32x4){ o[2][r4 * 4 + 0], o[2][r4 * 4 + 1], o[2][r4 * 4 + 2], o[2][r4 * 4 + 3] };
          *(f32x4*)&wout[base + 1 * 1024 + r4 * 256] =
            (f32x4){ o[3][r4 * 4 + 0], o[3][r4 * 4 + 1], o[3][r4 * 4 + 2], o[3][r4 * 4 + 3] };
        }
      } else {                         // g1 sends db 0,1
#pragma unroll
        for (int r4 = 0; r4 < 4; r4++) {
          *(f32x4*)&wout[base + 0 * 1024 + r4 * 256] =
            (f32x4){ o[0][r4 * 4 + 0], o[0][r4 * 4 + 1], o[0][r4 * 4 + 2], o[0][r4 * 4 + 3] };
          *(f32x4*)&wout[base + 1 * 1024 + r4 * 256] =
            (f32x4){ o[1][r4 * 4 + 0], o[1][r4 * 4 + 1], o[1][r4 * 4 + 2], o[1][r4 * 4 + 3] };
        }
      }
      __syncthreads();
      const float* rin = (const float*)&kbuf[g][0][0];
      float ltot = lown + lx[g ^ 1][wg][l31];
      if (hi == 0) li[g][wg][l31] = 1.f / ltot;
      f32x4 inv4[4];
#pragma unroll
      for (int tt = 0; tt < 4; tt++) inv4[tt] = *(const f32x4*)&li[g][wg][tt * 8 + 4 * hi];

      // O C-layout: col(lane)=d=db*32+l31, row(reg)=(r&3)+8*(r>>2)+4*hi
      unsigned short* ap0 = attn + ((size_t)(b * 2048 + qw)) * 2048 + h * 128 + l31;
      if (g == 0) {                    // g0 keeps db 0,1 -> cols 0,32
#pragma unroll
        for (int r4 = 0; r4 < 4; r4++) {
          f32x4 v0 = *(const f32x4*)&rin[base + 0 * 1024 + r4 * 256];
          f32x4 v1 = *(const f32x4*)&rin[base + 1 * 1024 + r4 * 256];
#pragma unroll
          for (int k = 0; k < 4; k++) {
            o[0][r4 * 4 + k] += v0[k];
            o[1][r4 * 4 + k] += v1[k];
          }
        }
#pragma unroll
        for (int r = 0; r < 16; r++) {
          int rowq = (r & 3) + 8 * (r >> 2) + 4 * hi;
          float iv = inv4[r >> 2][r & 3];
          ap0[(size_t)rowq * 2048 + 0]  = f2b(o[0][r] * iv);
          ap0[(size_t)rowq * 2048 + 32] = f2b(o[1][r] * iv);
        }
      } else {                         // g1 keeps db 2,3 -> cols 64,96
#pragma unroll
        for (int r4 = 0; r4 < 4; r4++) {
          f32x4 v0 = *(const f32x4*)&rin[base + 0 * 1024 + r4 * 256];
          f32x4 v1 = *(const f32x4*)&rin[base + 1 * 1024 + r4 * 256];
#pragma unroll
          for (int k = 0; k < 4; k++) {
            o[2][r4 * 4 + k] += v0[k];
            o[3][r4 * 4 + k] += v1[k];
          }
        }
#pragma unroll
        for (int r = 0; r < 16; r++) {
          int rowq = (r & 3) + 8 * (r >> 2) + 4 * hi;
          float iv = inv4[r >> 2][r & 3];
          ap0[(size_t)rowq * 2048 + 64] = f2b(o[2][r] * iv);
          ap0[(size_t)rowq * 2048 + 96] = f2b(o[3][r] * iv);
        }
      }
    }
  }
}

// ---------------------------------------------------------------------------
extern "C" void kernel_launch(void* const* d_in, const int* in_sizes, int n_in,
                              void* d_out, int out_size, void* d_ws, size_t ws_size,
                              hipStream_t stream) {
  const float* x  = (const float*)d_in[0];
  const float* Wq = (const float*)d_in[1];
  const float* Wk = (const float*)d_in[2];
  const float* Wv = (const float*)d_in[3];
  const float* Wo = (const float*)d_in[4];
  float* out = (float*)d_out;

  char* ws = (char*)d_ws;
  unsigned short* xb    = (unsigned short*)(ws);              // 16.78 MB (reused as attn)
  unsigned short* WqkvT = (unsigned short*)(ws + 16777216);   // 12.58 MB [3072][2048]
  unsigned short* WoT   = (unsigned short*)(ws + 29360128);   //  8.39 MB [2048][2048]
  unsigned short* Qm    = (unsigned short*)(ws + 62914560);   // 16.78 MB [B,H,S,D]
  unsigned short* Km    = (unsigned short*)(ws + 79691776);   //  4.19 MB [B,KV,S,D]
  unsigned short* Vtm   = (unsigned short*)(ws + 83886080);   //  4.19 MB [B,KV,D,S]
  unsigned short* attn  = xb;

  prep<<<14336, 256, 0, stream>>>(x, Wq, Wk, Wv, Wo, xb, WqkvT, WoT);

  gemm_qkv<<<dim3(24, 32), 256, 0, stream>>>(xb, WqkvT, Qm, Km, Vtm);

  flash2<<<dim3(8, 16, 2), 512, 0, stream>>>(Qm, Km, Vtm, attn);

  gemm_bt<<<dim3(16, 32), 256, 0, stream>>>(attn, WoT, out, 4096, 2048, 2048, 0);
}